// Round 1
// baseline (2973.119 us; speedup 1.0000x reference)
//
#include <hip/hip_runtime.h>
#include <math.h>

#define N_NODES 100000
#define N_EDGES 3200000
#define N_FEAT  512
#define N_HID   256
#define N_CLASS 40
#define K_HOPS  10

// ---------------- fused MLP: x0 = relu(feat@W1+b1)@W2 + b2 ----------------
// block 256 threads, 64 nodes per block. thread (g=t>>4, m=t&15) owns
// rows 4g..4g+3 and hidden cols {4m+64j+l : j,l in 0..3} (64 accumulators).
#define TM 64
#define KB 32

__global__ __launch_bounds__(256) void mlp_kernel(
    const float* __restrict__ feat, const float* __restrict__ W1,
    const float* __restrict__ b1, const float* __restrict__ W2,
    const float* __restrict__ b2, float* __restrict__ x0)
{
    __shared__ float As[TM][KB + 1];   // +1 pad -> 2-way (free) read conflicts
    __shared__ float Bs[KB][N_HID];

    const int t  = threadIdx.x;
    const int n0 = blockIdx.x * TM;
    const int g  = t >> 4;
    const int m  = t & 15;
    const int ar = t >> 2;   // staging row 0..63
    const int aq = t & 3;    // staging col quarter

    float hacc[4][16];
#pragma unroll
    for (int i = 0; i < 4; ++i)
#pragma unroll
        for (int jl = 0; jl < 16; ++jl) hacc[i][jl] = 0.f;

    for (int k0 = 0; k0 < N_FEAT; k0 += KB) {
        // ---- stage A tile: feat[n0..n0+63][k0..k0+31]
        {
            const int n = n0 + ar;
            float4 v0 = make_float4(0.f, 0.f, 0.f, 0.f), v1 = v0;
            if (n < N_NODES) {
                const float* p = &feat[(size_t)n * N_FEAT + k0 + 8 * aq];
                v0 = *(const float4*)(p);
                v1 = *(const float4*)(p + 4);
            }
            float* dst = &As[ar][8 * aq];
            dst[0] = v0.x; dst[1] = v0.y; dst[2] = v0.z; dst[3] = v0.w;
            dst[4] = v1.x; dst[5] = v1.y; dst[6] = v1.z; dst[7] = v1.w;
        }
        // ---- stage B tile: W1[k0..k0+31][0..255], contiguous float4 copy
#pragma unroll
        for (int qq = 0; qq < 8; ++qq) {
            const int f  = t + 256 * qq;   // float4 index in 2048-float4 tile
            const int kk = f >> 6;
            const int hq = f & 63;
            *(float4*)&Bs[kk][4 * hq] =
                *(const float4*)&W1[(size_t)(k0 + kk) * N_HID + 4 * hq];
        }
        __syncthreads();
#pragma unroll 4
        for (int kk = 0; kk < KB; ++kk) {
            float a[4];
#pragma unroll
            for (int i = 0; i < 4; ++i) a[i] = As[4 * g + i][kk];
#pragma unroll
            for (int j = 0; j < 4; ++j) {
                const float4 b = *(const float4*)&Bs[kk][4 * m + 64 * j];
#pragma unroll
                for (int i = 0; i < 4; ++i) {
                    hacc[i][4 * j + 0] += a[i] * b.x;
                    hacc[i][4 * j + 1] += a[i] * b.y;
                    hacc[i][4 * j + 2] += a[i] * b.z;
                    hacc[i][4 * j + 3] += a[i] * b.w;
                }
            }
        }
        __syncthreads();
    }

    // ---- bias + relu
#pragma unroll
    for (int j = 0; j < 4; ++j) {
        const float4 bb = *(const float4*)&b1[4 * m + 64 * j];
#pragma unroll
        for (int i = 0; i < 4; ++i) {
            hacc[i][4 * j + 0] = fmaxf(hacc[i][4 * j + 0] + bb.x, 0.f);
            hacc[i][4 * j + 1] = fmaxf(hacc[i][4 * j + 1] + bb.y, 0.f);
            hacc[i][4 * j + 2] = fmaxf(hacc[i][4 * j + 2] + bb.z, 0.f);
            hacc[i][4 * j + 3] = fmaxf(hacc[i][4 * j + 3] + bb.w, 0.f);
        }
    }

    // ---- GEMM2: out[r][c] = sum_h hrelu[r][h]*W2[h][c]; reduce over m-lanes
    for (int cb = 0; cb < 10; ++cb) {
        float p[4][4];
#pragma unroll
        for (int i = 0; i < 4; ++i)
#pragma unroll
            for (int c = 0; c < 4; ++c) p[i][c] = 0.f;
#pragma unroll
        for (int j = 0; j < 4; ++j) {
#pragma unroll
            for (int l = 0; l < 4; ++l) {
                const int hh = 4 * m + 64 * j + l;
                const float4 w = *(const float4*)&W2[hh * N_CLASS + 4 * cb];
#pragma unroll
                for (int i = 0; i < 4; ++i) {
                    const float hv = hacc[i][4 * j + l];
                    p[i][0] += hv * w.x; p[i][1] += hv * w.y;
                    p[i][2] += hv * w.z; p[i][3] += hv * w.w;
                }
            }
        }
        // butterfly reduce across the 16 m-lanes (xor masks 1,2,4,8 stay in-group)
#pragma unroll
        for (int off = 1; off < 16; off <<= 1) {
#pragma unroll
            for (int i = 0; i < 4; ++i) {
                p[i][0] += __shfl_xor(p[i][0], off);
                p[i][1] += __shfl_xor(p[i][1], off);
                p[i][2] += __shfl_xor(p[i][2], off);
                p[i][3] += __shfl_xor(p[i][3], off);
            }
        }
        if (m == 0) {
            const float4 bb = *(const float4*)&b2[4 * cb];
#pragma unroll
            for (int i = 0; i < 4; ++i) {
                const int n = n0 + 4 * g + i;
                if (n < N_NODES) {
                    float4 o;
                    o.x = p[i][0] + bb.x; o.y = p[i][1] + bb.y;
                    o.z = p[i][2] + bb.z; o.w = p[i][3] + bb.w;
                    *(float4*)&x0[(size_t)n * N_CLASS + 4 * cb] = o;
                }
            }
        }
    }
}

// ---------------- CSR build ----------------
__global__ void hist_kernel(const int* __restrict__ erow, int* __restrict__ deg)
{
    const int i = blockIdx.x * blockDim.x + threadIdx.x;
    if (i < N_EDGES) atomicAdd(&deg[erow[i]], 1);
}

__global__ void scan_partial(const int* __restrict__ deg, int* __restrict__ parts)
{
    __shared__ int sm[256];
    const int b = blockIdx.x, t = threadIdx.x;
    const int base = b * 1024 + t * 4;
    int s = 0;
#pragma unroll
    for (int u = 0; u < 4; ++u) {
        const int i = base + u;
        if (i < N_NODES) s += deg[i];
    }
    sm[t] = s;
    __syncthreads();
    for (int off = 128; off; off >>= 1) {
        if (t < off) sm[t] += sm[t + off];
        __syncthreads();
    }
    if (t == 0) parts[b] = sm[0];
}

#define NB_SCAN 98   // ceil(100000/1024)

__global__ void scan_spine(const int* __restrict__ parts, int* __restrict__ spine,
                           int* __restrict__ rowptr)
{
    __shared__ int sm[128];
    const int t = threadIdx.x;
    const int v = (t < NB_SCAN) ? parts[t] : 0;
    sm[t] = v;
    __syncthreads();
    for (int off = 1; off < 128; off <<= 1) {
        const int u = (t >= off) ? sm[t - off] : 0;
        __syncthreads();
        sm[t] += u;
        __syncthreads();
    }
    if (t < NB_SCAN) spine[t] = sm[t] - v;     // exclusive
    if (t == NB_SCAN - 1) rowptr[N_NODES] = sm[t];  // total = N_EDGES
}

__global__ void scan_final(const int* __restrict__ deg, const int* __restrict__ spine,
                           int* __restrict__ rowptr, int* __restrict__ cursor)
{
    __shared__ int sm[256];
    const int b = blockIdx.x, t = threadIdx.x;
    const int base = b * 1024 + t * 4;
    int d[4];
    int s = 0;
#pragma unroll
    for (int u = 0; u < 4; ++u) {
        const int i = base + u;
        d[u] = (i < N_NODES) ? deg[i] : 0;
        s += d[u];
    }
    sm[t] = s;
    __syncthreads();
    for (int off = 1; off < 256; off <<= 1) {
        const int u = (t >= off) ? sm[t - off] : 0;
        __syncthreads();
        sm[t] += u;
        __syncthreads();
    }
    int ex = sm[t] - s + spine[b];
#pragma unroll
    for (int u = 0; u < 4; ++u) {
        const int i = base + u;
        if (i < N_NODES) {
            rowptr[i] = ex;
            cursor[i] = ex;
            ex += d[u];
        }
    }
}

__global__ void scatter_kernel(const int* __restrict__ erow, const int* __restrict__ ecol,
                               const float* __restrict__ ew, int* __restrict__ cursor,
                               int* __restrict__ ccol, float* __restrict__ cwgt)
{
    const int i = blockIdx.x * blockDim.x + threadIdx.x;
    if (i < N_EDGES) {
        const int r = erow[i];
        const int p = atomicAdd(&cursor[r], 1);
        ccol[p] = ecol[i];
        cwgt[p] = ew[i];
    }
}

// ---------------- attention init (hop 0) ----------------
__device__ inline float wave_sum(float v)
{
#pragma unroll
    for (int o = 32; o; o >>= 1) v += __shfl_xor(v, o);
    return v;
}

__global__ __launch_bounds__(256) void attend0_kernel(
    const float* __restrict__ x, const float* __restrict__ Wa,
    const float* __restrict__ ba, float* __restrict__ acc)
{
    const int lane = threadIdx.x & 63;
    const int row  = blockIdx.x * 4 + (threadIdx.x >> 6);
    if (row >= N_NODES) return;
    const int  c   = lane;
    const bool act = c < N_CLASS;
    const float v  = act ? x[(size_t)row * N_CLASS + c] : 0.f;
    const float tt = act ? v * Wa[c] : 0.f;
    const float z  = wave_sum(tt) + ba[0];
    const float sc = 1.f / (1.f + expf(-z));
    if (act) acc[(size_t)row * N_CLASS + c] = sc * v;
}

// ---------------- one hop: xout = segsum(w * xin[col]); acc += sigmoid(.)*xout
__global__ __launch_bounds__(256) void hop_kernel(
    const int* __restrict__ rowptr, const int* __restrict__ ccol,
    const float* __restrict__ cwgt, const float* __restrict__ xin,
    float* __restrict__ xout, float* __restrict__ acc,
    const float* __restrict__ Wa, const float* __restrict__ ba)
{
    const int lane = threadIdx.x & 63;
    const int row  = blockIdx.x * 4 + (threadIdx.x >> 6);
    if (row >= N_NODES) return;
    const int  c   = lane;
    const bool act = c < N_CLASS;

    const int e0 = rowptr[row];
    const int e1 = rowptr[row + 1];

    float s = 0.f;
    int e = e0;
    for (; e + 1 < e1; e += 2) {
        const int   c0 = ccol[e];
        const int   c1 = ccol[e + 1];
        const float w0 = cwgt[e];
        const float w1 = cwgt[e + 1];
        const float v0 = act ? xin[(size_t)c0 * N_CLASS + c] : 0.f;
        const float v1 = act ? xin[(size_t)c1 * N_CLASS + c] : 0.f;
        s += w0 * v0;
        s += w1 * v1;
    }
    if (e < e1) {
        const int   c0 = ccol[e];
        const float w0 = cwgt[e];
        const float v0 = act ? xin[(size_t)c0 * N_CLASS + c] : 0.f;
        s += w0 * v0;
    }

    if (act) xout[(size_t)row * N_CLASS + c] = s;

    const float tt = act ? s * Wa[c] : 0.f;
    const float z  = wave_sum(tt) + ba[0];
    const float sc = 1.f / (1.f + expf(-z));
    if (act) acc[(size_t)row * N_CLASS + c] += sc * s;
}

// ---------------- log_softmax over 40 classes ----------------
__global__ __launch_bounds__(256) void logsoftmax_kernel(
    const float* __restrict__ acc, float* __restrict__ out)
{
    const int lane = threadIdx.x & 63;
    const int row  = blockIdx.x * 4 + (threadIdx.x >> 6);
    if (row >= N_NODES) return;
    const int  c   = lane;
    const bool act = c < N_CLASS;

    float v = act ? acc[(size_t)row * N_CLASS + c] : -INFINITY;
    float mx = v;
#pragma unroll
    for (int o = 32; o; o >>= 1) mx = fmaxf(mx, __shfl_xor(mx, o));
    const float e = act ? expf(v - mx) : 0.f;
    const float s = wave_sum(e);
    if (act) out[(size_t)row * N_CLASS + c] = v - mx - logf(s);
}

extern "C" void kernel_launch(void* const* d_in, const int* in_sizes, int n_in,
                              void* d_out, int out_size, void* d_ws, size_t ws_size,
                              hipStream_t stream)
{
    (void)in_sizes; (void)n_in; (void)out_size; (void)ws_size;
    const float* feat = (const float*)d_in[0];
    const int*   erow = (const int*)d_in[1];
    const int*   ecol = (const int*)d_in[2];
    const float* ew   = (const float*)d_in[3];
    const float* W1   = (const float*)d_in[4];
    const float* b1   = (const float*)d_in[5];
    const float* W2   = (const float*)d_in[6];
    const float* b2   = (const float*)d_in[7];
    const float* Wa   = (const float*)d_in[8];
    const float* ba   = (const float*)d_in[9];
    float* out = (float*)d_out;

    char* ws = (char*)d_ws;
    size_t off = 0;
    auto take = [&](size_t bytes) -> char* {
        char* p = ws + off;
        off += (bytes + 255) & ~(size_t)255;
        return p;
    };
    float* xb0    = (float*)take((size_t)N_NODES * N_CLASS * 4);
    float* xb1    = (float*)take((size_t)N_NODES * N_CLASS * 4);
    float* acc    = (float*)take((size_t)N_NODES * N_CLASS * 4);
    int*   deg    = (int*)take((size_t)N_NODES * 4);
    int*   rowptr = (int*)take((size_t)(N_NODES + 1) * 4);
    int*   cursor = (int*)take((size_t)N_NODES * 4);
    int*   parts  = (int*)take(4096);
    int*   spine  = (int*)take(4096);
    int*   ccol   = (int*)take((size_t)N_EDGES * 4);
    float* cwgt   = (float*)take((size_t)N_EDGES * 4);

    hipMemsetAsync(deg, 0, (size_t)N_NODES * 4, stream);

    mlp_kernel<<<(N_NODES + TM - 1) / TM, 256, 0, stream>>>(feat, W1, b1, W2, b2, xb0);
    hist_kernel<<<N_EDGES / 256, 256, 0, stream>>>(erow, deg);
    scan_partial<<<NB_SCAN, 256, 0, stream>>>(deg, parts);
    scan_spine<<<1, 128, 0, stream>>>(parts, spine, rowptr);
    scan_final<<<NB_SCAN, 256, 0, stream>>>(deg, spine, rowptr, cursor);
    scatter_kernel<<<N_EDGES / 256, 256, 0, stream>>>(erow, ecol, ew, cursor, ccol, cwgt);

    attend0_kernel<<<N_NODES / 4, 256, 0, stream>>>(xb0, Wa, ba, acc);

    const float* xin = xb0;
    float* xout = xb1;
    for (int k = 0; k < K_HOPS; ++k) {
        hop_kernel<<<N_NODES / 4, 256, 0, stream>>>(rowptr, ccol, cwgt, xin, xout, acc, Wa, ba);
        float* tmp = (float*)xin;
        xin  = xout;
        xout = tmp;
    }

    logsoftmax_kernel<<<N_NODES / 4, 256, 0, stream>>>(acc, out);
}

// Round 2
// 1897.199 us; speedup vs baseline: 1.5671x; 1.5671x over previous
//
#include <hip/hip_runtime.h>
#include <math.h>

#define N_NODES 100000
#define N_EDGES 3200000
#define N_FEAT  512
#define N_HID   256
#define N_CLASS 40
#define K_HOPS  10

typedef __attribute__((ext_vector_type(8))) short short8;
typedef __attribute__((ext_vector_type(4))) float float4v;

__device__ inline short f2bf(float f)
{
    union { float f; unsigned u; } v; v.f = f;
    unsigned r = v.u + 0x7FFF + ((v.u >> 16) & 1);   // RNE
    return (short)(r >> 16);
}

// ---------------- weight packing (once per launch, trivial) ----------------
// W1p[(kb*256 + n)*32 + kl] = bf16(W1[kb*32+kl][n]), kb=0..15
__global__ void pack_w1(const float* __restrict__ W1, short* __restrict__ W1p)
{
    const int id = blockIdx.x * 256 + threadIdx.x;   // 0..4095
    const int kb = id >> 8, n = id & 255;
    short tmp[32];
#pragma unroll
    for (int kl = 0; kl < 32; ++kl)
        tmp[kl] = f2bf(W1[(size_t)(kb * 32 + kl) * N_HID + n]);
    short8* dst = (short8*)&W1p[id * 32];
#pragma unroll
    for (int j = 0; j < 4; ++j) dst[j] = *(short8*)&tmp[j * 8];
}

// W2p[(kb*48 + n)*32 + kl] = n<40 ? bf16(W2[kb*32+kl][n]) : 0, kb=0..7
__global__ void pack_w2(const float* __restrict__ W2, short* __restrict__ W2p)
{
    const int id = blockIdx.x * 256 + threadIdx.x;
    if (id >= 8 * 48) return;
    const int kb = id / 48, n = id % 48;
    short tmp[32];
#pragma unroll
    for (int kl = 0; kl < 32; ++kl)
        tmp[kl] = (n < N_CLASS) ? f2bf(W2[(size_t)(kb * 32 + kl) * N_CLASS + n]) : (short)0;
    short8* dst = (short8*)&W2p[id * 32];
#pragma unroll
    for (int j = 0; j < 4; ++j) dst[j] = *(short8*)&tmp[j * 8];
}

// ---------------- fused MFMA MLP: x0 = relu(feat@W1+b1)@W2 + b2 ----------------
// block: 256 thr = 4 waves, 64 rows x 256 hidden. Wave w: col-tiles 4w..4w+3,
// all 4 row-tiles (4x4 frags, 8 frag loads / 16 MFMAs per K-step).
__global__ __launch_bounds__(256) void mlp_mfma(
    const float* __restrict__ feat, const short* __restrict__ W1p,
    const float* __restrict__ b1, const short* __restrict__ W2p,
    const float* __restrict__ b2, float* __restrict__ x0)
{
    __shared__ __align__(16) short smem[64 * 264];          // 33792 B
    short (*As)[40]  = (short(*)[40])smem;                  // aliased (phase 1)
    short (*Hs)[264] = (short(*)[264])smem;                 // aliased (phase 2)

    const int t    = threadIdx.x;
    const int wave = t >> 6;
    const int lane = t & 63;
    const int q    = lane >> 4;      // quad 0..3
    const int m    = lane & 15;
    const int n0   = blockIdx.x * 64;
    const int colbase = wave * 64;

    float4v acc[4][4];
#pragma unroll
    for (int i = 0; i < 4; ++i)
#pragma unroll
        for (int j = 0; j < 4; ++j) acc[i][j] = (float4v)0.f;

    // ---- GEMM1: K = 512, 16 steps of 32
    for (int kb = 0; kb < 16; ++kb) {
        const int k0 = kb * 32;
        __syncthreads();
        // stage A: 64 rows x 32 k, fp32 -> bf16 (coalesced, zero-pad OOB rows)
        {
            const int r  = t >> 2;
            const int kq = t & 3;
            const int n  = n0 + r;
            float f[8];
            if (n < N_NODES) {
                const float* p = &feat[(size_t)n * N_FEAT + k0 + 8 * kq];
                float4 v0 = *(const float4*)p;
                float4 v1 = *(const float4*)(p + 4);
                f[0]=v0.x; f[1]=v0.y; f[2]=v0.z; f[3]=v0.w;
                f[4]=v1.x; f[5]=v1.y; f[6]=v1.z; f[7]=v1.w;
            } else {
#pragma unroll
                for (int j = 0; j < 8; ++j) f[j] = 0.f;
            }
            short8 st;
#pragma unroll
            for (int j = 0; j < 8; ++j) st[j] = f2bf(f[j]);
            *(short8*)&As[r][8 * kq] = st;
        }
        __syncthreads();

        short8 af[4], bf[4];
#pragma unroll
        for (int rt = 0; rt < 4; ++rt)
            af[rt] = *(const short8*)&As[rt * 16 + m][q * 8];
#pragma unroll
        for (int ct = 0; ct < 4; ++ct) {
            const int off = (kb * 256 + colbase + ct * 16 + m) * 32 + q * 8;
            bf[ct] = *(const short8*)&W1p[off];
        }
#pragma unroll
        for (int rt = 0; rt < 4; ++rt)
#pragma unroll
            for (int ct = 0; ct < 4; ++ct)
                acc[rt][ct] = __builtin_amdgcn_mfma_f32_16x16x32_bf16(
                    af[rt], bf[ct], acc[rt][ct], 0, 0, 0);
    }

    // ---- bias + relu -> Hs (bf16), aliases As so sync first
    __syncthreads();
#pragma unroll
    for (int ct = 0; ct < 4; ++ct) {
        const int col = colbase + ct * 16 + m;
        const float bias = b1[col];
#pragma unroll
        for (int rt = 0; rt < 4; ++rt) {
            const float4v d = acc[rt][ct];
#pragma unroll
            for (int r = 0; r < 4; ++r) {
                const float hv = fmaxf(d[r] + bias, 0.f);
                Hs[rt * 16 + q * 4 + r][col] = f2bf(hv);
            }
        }
    }
    __syncthreads();

    // ---- GEMM2: y[16][48] per wave, K = 256, 8 steps
    float4v acc2[3];
#pragma unroll
    for (int ct = 0; ct < 3; ++ct) acc2[ct] = (float4v)0.f;
#pragma unroll
    for (int kb = 0; kb < 8; ++kb) {
        const short8 a2 = *(const short8*)&Hs[wave * 16 + m][kb * 32 + q * 8];
#pragma unroll
        for (int ct = 0; ct < 3; ++ct) {
            const int off = (kb * 48 + ct * 16 + m) * 32 + q * 8;
            const short8 b2f = *(const short8*)&W2p[off];
            acc2[ct] = __builtin_amdgcn_mfma_f32_16x16x32_bf16(a2, b2f, acc2[ct], 0, 0, 0);
        }
    }
#pragma unroll
    for (int ct = 0; ct < 3; ++ct) {
        const int col = ct * 16 + m;
        if (col < N_CLASS) {
            const float bias = b2[col];
#pragma unroll
            for (int r = 0; r < 4; ++r) {
                const int row = n0 + wave * 16 + q * 4 + r;
                if (row < N_NODES)
                    x0[(size_t)row * N_CLASS + col] = acc2[ct][r] + bias;
            }
        }
    }
}

// ---------------- CSR build ----------------
__global__ void hist_kernel(const int* __restrict__ erow, int* __restrict__ deg)
{
    const int i = blockIdx.x * blockDim.x + threadIdx.x;
    if (i < N_EDGES) atomicAdd(&deg[erow[i]], 1);
}

__global__ void scan_partial(const int* __restrict__ deg, int* __restrict__ parts)
{
    __shared__ int sm[256];
    const int b = blockIdx.x, t = threadIdx.x;
    const int base = b * 1024 + t * 4;
    int s = 0;
#pragma unroll
    for (int u = 0; u < 4; ++u) {
        const int i = base + u;
        if (i < N_NODES) s += deg[i];
    }
    sm[t] = s;
    __syncthreads();
    for (int off = 128; off; off >>= 1) {
        if (t < off) sm[t] += sm[t + off];
        __syncthreads();
    }
    if (t == 0) parts[b] = sm[0];
}

#define NB_SCAN 98   // ceil(100000/1024)

__global__ void scan_spine(const int* __restrict__ parts, int* __restrict__ spine,
                           int* __restrict__ rowptr)
{
    __shared__ int sm[128];
    const int t = threadIdx.x;
    const int v = (t < NB_SCAN) ? parts[t] : 0;
    sm[t] = v;
    __syncthreads();
    for (int off = 1; off < 128; off <<= 1) {
        const int u = (t >= off) ? sm[t - off] : 0;
        __syncthreads();
        sm[t] += u;
        __syncthreads();
    }
    if (t < NB_SCAN) spine[t] = sm[t] - v;          // exclusive
    if (t == NB_SCAN - 1) rowptr[N_NODES] = sm[t];  // total = N_EDGES
}

__global__ void scan_final(const int* __restrict__ deg, const int* __restrict__ spine,
                           int* __restrict__ rowptr, int* __restrict__ cursor)
{
    __shared__ int sm[256];
    const int b = blockIdx.x, t = threadIdx.x;
    const int base = b * 1024 + t * 4;
    int d[4];
    int s = 0;
#pragma unroll
    for (int u = 0; u < 4; ++u) {
        const int i = base + u;
        d[u] = (i < N_NODES) ? deg[i] : 0;
        s += d[u];
    }
    sm[t] = s;
    __syncthreads();
    for (int off = 1; off < 256; off <<= 1) {
        const int u = (t >= off) ? sm[t - off] : 0;
        __syncthreads();
        sm[t] += u;
        __syncthreads();
    }
    int ex = sm[t] - s + spine[b];
#pragma unroll
    for (int u = 0; u < 4; ++u) {
        const int i = base + u;
        if (i < N_NODES) {
            rowptr[i] = ex;
            cursor[i] = ex;
            ex += d[u];
        }
    }
}

__global__ void scatter_kernel(const int* __restrict__ erow, const int* __restrict__ ecol,
                               const float* __restrict__ ew, int* __restrict__ cursor,
                               int* __restrict__ ccol, float* __restrict__ cwgt)
{
    const int i = blockIdx.x * blockDim.x + threadIdx.x;
    if (i < N_EDGES) {
        const int r = erow[i];
        const int p = atomicAdd(&cursor[r], 1);
        ccol[p] = ecol[i];
        cwgt[p] = ew[i];
    }
}

// ---------------- attention init (hop 0) ----------------
__device__ inline float wave_sum(float v)
{
#pragma unroll
    for (int o = 32; o; o >>= 1) v += __shfl_xor(v, o);
    return v;
}

__global__ __launch_bounds__(256) void attend0_kernel(
    const float* __restrict__ x, const float* __restrict__ Wa,
    const float* __restrict__ ba, float* __restrict__ acc)
{
    const int lane = threadIdx.x & 63;
    const int row  = blockIdx.x * 4 + (threadIdx.x >> 6);
    if (row >= N_NODES) return;
    const int  c   = lane;
    const bool act = c < N_CLASS;
    const float v  = act ? x[(size_t)row * N_CLASS + c] : 0.f;
    const float tt = act ? v * Wa[c] : 0.f;
    const float z  = wave_sum(tt) + ba[0];
    const float sc = 1.f / (1.f + expf(-z));
    if (act) acc[(size_t)row * N_CLASS + c] = sc * v;
}

// ------- one hop: xout = segsum(w * xin[col]); acc += sigmoid(xout.Wa+ba)*xout
// wave per row; slot = lane>>4 (4 edges in flight), q = lane&15 (10 active,
// float4 over classes).
__global__ __launch_bounds__(256) void hop_kernel(
    const int* __restrict__ rowptr, const int* __restrict__ ccol,
    const float* __restrict__ cwgt, const float* __restrict__ xin,
    float* __restrict__ xout, float* __restrict__ acc,
    const float* __restrict__ Wa, const float* __restrict__ ba)
{
    const int lane = threadIdx.x & 63;
    const int row  = blockIdx.x * 4 + (threadIdx.x >> 6);
    if (row >= N_NODES) return;
    const int  slot = lane >> 4;
    const int  q    = lane & 15;
    const bool act  = q < 10;

    const int e0 = rowptr[row];
    const int e1 = rowptr[row + 1];

    float4 s = make_float4(0.f, 0.f, 0.f, 0.f);
    for (int e = e0; e < e1; e += 4) {
        const int  ee  = e + slot;
        const bool inb = ee < e1;
        const int   c  = inb ? ccol[ee] : 0;
        const float w  = inb ? cwgt[ee] : 0.f;
        if (act) {
            const float4 v = *(const float4*)&xin[(size_t)c * N_CLASS + 4 * q];
            s.x += w * v.x; s.y += w * v.y; s.z += w * v.z; s.w += w * v.w;
        }
    }
    // reduce across the 4 slots
#pragma unroll
    for (int o = 16; o <= 32; o <<= 1) {
        s.x += __shfl_xor(s.x, o);
        s.y += __shfl_xor(s.y, o);
        s.z += __shfl_xor(s.z, o);
        s.w += __shfl_xor(s.w, o);
    }
    // attention score
    float tq = 0.f;
    if (act) {
        const float4 wa = *(const float4*)&Wa[4 * q];
        tq = s.x * wa.x + s.y * wa.y + s.z * wa.z + s.w * wa.w;
    }
#pragma unroll
    for (int o = 1; o < 16; o <<= 1) tq += __shfl_xor(tq, o);
    const float z  = tq + ba[0];
    const float sc = 1.f / (1.f + expf(-z));

    if (act && slot == 0) {
        *(float4*)&xout[(size_t)row * N_CLASS + 4 * q] = s;
        float4* ap = (float4*)&acc[(size_t)row * N_CLASS + 4 * q];
        float4 a = *ap;
        a.x += sc * s.x; a.y += sc * s.y; a.z += sc * s.z; a.w += sc * s.w;
        *ap = a;
    }
}

// ---------------- log_softmax over 40 classes ----------------
__global__ __launch_bounds__(256) void logsoftmax_kernel(
    const float* __restrict__ acc, float* __restrict__ out)
{
    const int lane = threadIdx.x & 63;
    const int row  = blockIdx.x * 4 + (threadIdx.x >> 6);
    if (row >= N_NODES) return;
    const int  c   = lane;
    const bool act = c < N_CLASS;

    float v = act ? acc[(size_t)row * N_CLASS + c] : -INFINITY;
    float mx = v;
#pragma unroll
    for (int o = 32; o; o >>= 1) mx = fmaxf(mx, __shfl_xor(mx, o));
    const float e = act ? expf(v - mx) : 0.f;
    const float s = wave_sum(e);
    if (act) out[(size_t)row * N_CLASS + c] = v - mx - logf(s);
}

extern "C" void kernel_launch(void* const* d_in, const int* in_sizes, int n_in,
                              void* d_out, int out_size, void* d_ws, size_t ws_size,
                              hipStream_t stream)
{
    (void)in_sizes; (void)n_in; (void)out_size; (void)ws_size;
    const float* feat = (const float*)d_in[0];
    const int*   erow = (const int*)d_in[1];
    const int*   ecol = (const int*)d_in[2];
    const float* ew   = (const float*)d_in[3];
    const float* W1   = (const float*)d_in[4];
    const float* b1   = (const float*)d_in[5];
    const float* W2   = (const float*)d_in[6];
    const float* b2   = (const float*)d_in[7];
    const float* Wa   = (const float*)d_in[8];
    const float* ba   = (const float*)d_in[9];
    float* out = (float*)d_out;

    char* ws = (char*)d_ws;
    size_t off = 0;
    auto take = [&](size_t bytes) -> char* {
        char* p = ws + off;
        off += (bytes + 255) & ~(size_t)255;
        return p;
    };
    float* xb0    = (float*)take((size_t)N_NODES * N_CLASS * 4);
    float* xb1    = (float*)take((size_t)N_NODES * N_CLASS * 4);
    float* acc    = (float*)take((size_t)N_NODES * N_CLASS * 4);
    int*   deg    = (int*)take((size_t)N_NODES * 4);
    int*   rowptr = (int*)take((size_t)(N_NODES + 1) * 4);
    int*   cursor = (int*)take((size_t)N_NODES * 4);
    int*   parts  = (int*)take(4096);
    int*   spine  = (int*)take(4096);
    short* W1p    = (short*)take((size_t)N_FEAT * N_HID * 2);
    short* W2p    = (short*)take((size_t)N_HID * 48 * 2);
    int*   ccol   = (int*)take((size_t)N_EDGES * 4);
    float* cwgt   = (float*)take((size_t)N_EDGES * 4);

    hipMemsetAsync(deg, 0, (size_t)N_NODES * 4, stream);

    pack_w1<<<16, 256, 0, stream>>>(W1, W1p);
    pack_w2<<<2, 256, 0, stream>>>(W2, W2p);
    mlp_mfma<<<(N_NODES + 63) / 64, 256, 0, stream>>>(feat, W1p, b1, W2p, b2, xb0);

    hist_kernel<<<N_EDGES / 256, 256, 0, stream>>>(erow, deg);
    scan_partial<<<NB_SCAN, 256, 0, stream>>>(deg, parts);
    scan_spine<<<1, 128, 0, stream>>>(parts, spine, rowptr);
    scan_final<<<NB_SCAN, 256, 0, stream>>>(deg, spine, rowptr, cursor);
    scatter_kernel<<<N_EDGES / 256, 256, 0, stream>>>(erow, ecol, ew, cursor, ccol, cwgt);

    attend0_kernel<<<N_NODES / 4, 256, 0, stream>>>(xb0, Wa, ba, acc);

    const float* xin = xb0;
    float* xout = xb1;
    for (int k = 0; k < K_HOPS; ++k) {
        hop_kernel<<<N_NODES / 4, 256, 0, stream>>>(rowptr, ccol, cwgt, xin, xout, acc, Wa, ba);
        float* tmp = (float*)xin;
        xin  = xout;
        xout = tmp;
    }

    logsoftmax_kernel<<<N_NODES / 4, 256, 0, stream>>>(acc, out);
}

// Round 3
// 1854.700 us; speedup vs baseline: 1.6030x; 1.0229x over previous
//
#include <hip/hip_runtime.h>
#include <math.h>

#define N_NODES 100000
#define N_EDGES 3200000
#define N_FEAT  512
#define N_HID   256
#define N_CLASS 40
#define K_HOPS  10

typedef __attribute__((ext_vector_type(8))) short short8;
typedef __attribute__((ext_vector_type(4))) float float4v;

__device__ inline short f2bf(float f)
{
    union { float f; unsigned u; } v; v.f = f;
    unsigned r = v.u + 0x7FFF + ((v.u >> 16) & 1);   // RNE
    return (short)(r >> 16);
}

__device__ inline float bf2f(unsigned short u)
{
    union { unsigned u; float f; } v; v.u = (unsigned)u << 16;
    return v.f;
}

// ---------------- weight packing (once per launch, trivial) ----------------
__global__ void pack_w1(const float* __restrict__ W1, short* __restrict__ W1p)
{
    const int id = blockIdx.x * 256 + threadIdx.x;   // 0..4095
    const int kb = id >> 8, n = id & 255;
    short tmp[32];
#pragma unroll
    for (int kl = 0; kl < 32; ++kl)
        tmp[kl] = f2bf(W1[(size_t)(kb * 32 + kl) * N_HID + n]);
    short8* dst = (short8*)&W1p[id * 32];
#pragma unroll
    for (int j = 0; j < 4; ++j) dst[j] = *(short8*)&tmp[j * 8];
}

__global__ void pack_w2(const float* __restrict__ W2, short* __restrict__ W2p)
{
    const int id = blockIdx.x * 256 + threadIdx.x;
    if (id >= 8 * 48) return;
    const int kb = id / 48, n = id % 48;
    short tmp[32];
#pragma unroll
    for (int kl = 0; kl < 32; ++kl)
        tmp[kl] = (n < N_CLASS) ? f2bf(W2[(size_t)(kb * 32 + kl) * N_CLASS + n]) : (short)0;
    short8* dst = (short8*)&W2p[id * 32];
#pragma unroll
    for (int j = 0; j < 4; ++j) dst[j] = *(short8*)&tmp[j * 8];
}

// ---------------- fused MFMA MLP: x0 = relu(feat@W1+b1)@W2 + b2 (bf16 out) ----
__global__ __launch_bounds__(256) void mlp_mfma(
    const float* __restrict__ feat, const short* __restrict__ W1p,
    const float* __restrict__ b1, const short* __restrict__ W2p,
    const float* __restrict__ b2, unsigned short* __restrict__ x0)
{
    __shared__ __align__(16) short smem[64 * 264];          // 33792 B
    short (*As)[40]  = (short(*)[40])smem;                  // aliased (phase 1)
    short (*Hs)[264] = (short(*)[264])smem;                 // aliased (phase 2)

    const int t    = threadIdx.x;
    const int wave = t >> 6;
    const int lane = t & 63;
    const int q    = lane >> 4;      // quad 0..3
    const int m    = lane & 15;
    const int n0   = blockIdx.x * 64;
    const int colbase = wave * 64;

    float4v acc[4][4];
#pragma unroll
    for (int i = 0; i < 4; ++i)
#pragma unroll
        for (int j = 0; j < 4; ++j) acc[i][j] = (float4v)0.f;

    for (int kb = 0; kb < 16; ++kb) {
        const int k0 = kb * 32;
        __syncthreads();
        {
            const int r  = t >> 2;
            const int kq = t & 3;
            const int n  = n0 + r;
            float f[8];
            if (n < N_NODES) {
                const float* p = &feat[(size_t)n * N_FEAT + k0 + 8 * kq];
                float4 v0 = *(const float4*)p;
                float4 v1 = *(const float4*)(p + 4);
                f[0]=v0.x; f[1]=v0.y; f[2]=v0.z; f[3]=v0.w;
                f[4]=v1.x; f[5]=v1.y; f[6]=v1.z; f[7]=v1.w;
            } else {
#pragma unroll
                for (int j = 0; j < 8; ++j) f[j] = 0.f;
            }
            short8 st;
#pragma unroll
            for (int j = 0; j < 8; ++j) st[j] = f2bf(f[j]);
            *(short8*)&As[r][8 * kq] = st;
        }
        __syncthreads();

        short8 af[4], bfr[4];
#pragma unroll
        for (int rt = 0; rt < 4; ++rt)
            af[rt] = *(const short8*)&As[rt * 16 + m][q * 8];
#pragma unroll
        for (int ct = 0; ct < 4; ++ct) {
            const int off = (kb * 256 + colbase + ct * 16 + m) * 32 + q * 8;
            bfr[ct] = *(const short8*)&W1p[off];
        }
#pragma unroll
        for (int rt = 0; rt < 4; ++rt)
#pragma unroll
            for (int ct = 0; ct < 4; ++ct)
                acc[rt][ct] = __builtin_amdgcn_mfma_f32_16x16x32_bf16(
                    af[rt], bfr[ct], acc[rt][ct], 0, 0, 0);
    }

    __syncthreads();
#pragma unroll
    for (int ct = 0; ct < 4; ++ct) {
        const int col = colbase + ct * 16 + m;
        const float bias = b1[col];
#pragma unroll
        for (int rt = 0; rt < 4; ++rt) {
            const float4v d = acc[rt][ct];
#pragma unroll
            for (int r = 0; r < 4; ++r) {
                const float hv = fmaxf(d[r] + bias, 0.f);
                Hs[rt * 16 + q * 4 + r][col] = f2bf(hv);
            }
        }
    }
    __syncthreads();

    float4v acc2[3];
#pragma unroll
    for (int ct = 0; ct < 3; ++ct) acc2[ct] = (float4v)0.f;
#pragma unroll
    for (int kb = 0; kb < 8; ++kb) {
        const short8 a2 = *(const short8*)&Hs[wave * 16 + m][kb * 32 + q * 8];
#pragma unroll
        for (int ct = 0; ct < 3; ++ct) {
            const int off = (kb * 48 + ct * 16 + m) * 32 + q * 8;
            const short8 b2f = *(const short8*)&W2p[off];
            acc2[ct] = __builtin_amdgcn_mfma_f32_16x16x32_bf16(a2, b2f, acc2[ct], 0, 0, 0);
        }
    }
#pragma unroll
    for (int ct = 0; ct < 3; ++ct) {
        const int col = ct * 16 + m;
        if (col < N_CLASS) {
            const float bias = b2[col];
#pragma unroll
            for (int r = 0; r < 4; ++r) {
                const int row = n0 + wave * 16 + q * 4 + r;
                if (row < N_NODES)
                    x0[(size_t)row * N_CLASS + col] = (unsigned short)f2bf(acc2[ct][r] + bias);
            }
        }
    }
}

// ---------------- CSR build ----------------
__global__ void hist_kernel(const int* __restrict__ erow, int* __restrict__ deg)
{
    const int i = blockIdx.x * blockDim.x + threadIdx.x;
    if (i < N_EDGES) atomicAdd(&deg[erow[i]], 1);
}

__global__ void scan_partial(const int* __restrict__ deg, int* __restrict__ parts)
{
    __shared__ int sm[256];
    const int b = blockIdx.x, t = threadIdx.x;
    const int base = b * 1024 + t * 4;
    int s = 0;
#pragma unroll
    for (int u = 0; u < 4; ++u) {
        const int i = base + u;
        if (i < N_NODES) s += deg[i];
    }
    sm[t] = s;
    __syncthreads();
    for (int off = 128; off; off >>= 1) {
        if (t < off) sm[t] += sm[t + off];
        __syncthreads();
    }
    if (t == 0) parts[b] = sm[0];
}

#define NB_SCAN 98   // ceil(100000/1024)

__global__ void scan_spine(const int* __restrict__ parts, int* __restrict__ spine,
                           int* __restrict__ rowptr)
{
    __shared__ int sm[128];
    const int t = threadIdx.x;
    const int v = (t < NB_SCAN) ? parts[t] : 0;
    sm[t] = v;
    __syncthreads();
    for (int off = 1; off < 128; off <<= 1) {
        const int u = (t >= off) ? sm[t - off] : 0;
        __syncthreads();
        sm[t] += u;
        __syncthreads();
    }
    if (t < NB_SCAN) spine[t] = sm[t] - v;          // exclusive
    if (t == NB_SCAN - 1) rowptr[N_NODES] = sm[t];  // total = N_EDGES
}

__global__ void scan_final(const int* __restrict__ deg, const int* __restrict__ spine,
                           int* __restrict__ rowptr, int* __restrict__ cursor)
{
    __shared__ int sm[256];
    const int b = blockIdx.x, t = threadIdx.x;
    const int base = b * 1024 + t * 4;
    int d[4];
    int s = 0;
#pragma unroll
    for (int u = 0; u < 4; ++u) {
        const int i = base + u;
        d[u] = (i < N_NODES) ? deg[i] : 0;
        s += d[u];
    }
    sm[t] = s;
    __syncthreads();
    for (int off = 1; off < 256; off <<= 1) {
        const int u = (t >= off) ? sm[t - off] : 0;
        __syncthreads();
        sm[t] += u;
        __syncthreads();
    }
    int ex = sm[t] - s + spine[b];
#pragma unroll
    for (int u = 0; u < 4; ++u) {
        const int i = base + u;
        if (i < N_NODES) {
            rowptr[i] = ex;
            cursor[i] = ex;
            ex += d[u];
        }
    }
}

// single 8B packed record per edge: halves scattered-store line touches
__global__ void scatter_kernel(const int* __restrict__ erow, const int* __restrict__ ecol,
                               const float* __restrict__ ew, int* __restrict__ cursor,
                               int2* __restrict__ epack)
{
    const int i = blockIdx.x * blockDim.x + threadIdx.x;
    if (i < N_EDGES) {
        const int r = erow[i];
        const int p = atomicAdd(&cursor[r], 1);
        int2 rec;
        rec.x = ecol[i];
        rec.y = __float_as_int(ew[i]);
        epack[p] = rec;
    }
}

// ---------------- attention init (hop 0) ----------------
__device__ inline float wave_sum(float v)
{
#pragma unroll
    for (int o = 32; o; o >>= 1) v += __shfl_xor(v, o);
    return v;
}

__global__ __launch_bounds__(256) void attend0_kernel(
    const unsigned short* __restrict__ x, const float* __restrict__ Wa,
    const float* __restrict__ ba, float* __restrict__ acc)
{
    const int lane = threadIdx.x & 63;
    const int row  = blockIdx.x * 4 + (threadIdx.x >> 6);
    if (row >= N_NODES) return;
    const int  c   = lane;
    const bool act = c < N_CLASS;
    const float v  = act ? bf2f(x[(size_t)row * N_CLASS + c]) : 0.f;
    const float tt = act ? v * Wa[c] : 0.f;
    const float z  = wave_sum(tt) + ba[0];
    const float sc = 1.f / (1.f + expf(-z));
    if (act) acc[(size_t)row * N_CLASS + c] = sc * v;
}

// ------- one hop: s = segsum(w * xin[col]) fp32 from bf16 gathers;
//         xout = bf16(s); acc += sigmoid(s.Wa+ba) * s
// wave per row; slot = lane>>4 (4 edges in flight), q = lane&15 (10 active,
// 4 bf16 classes = 8B per lane).
__global__ __launch_bounds__(256) void hop_kernel(
    const int* __restrict__ rowptr, const int2* __restrict__ epack,
    const unsigned short* __restrict__ xin,
    unsigned short* __restrict__ xout, float* __restrict__ acc,
    const float* __restrict__ Wa, const float* __restrict__ ba)
{
    const int lane = threadIdx.x & 63;
    const int row  = blockIdx.x * 4 + (threadIdx.x >> 6);
    if (row >= N_NODES) return;
    const int  slot = lane >> 4;
    const int  q    = lane & 15;
    const bool act  = q < 10;

    const int e0 = rowptr[row];
    const int e1 = rowptr[row + 1];

    float4 s = make_float4(0.f, 0.f, 0.f, 0.f);
    for (int e = e0; e < e1; e += 4) {
        const int  ee  = e + slot;
        int   col = 0;
        float w   = 0.f;
        if (ee < e1) {
            const int2 rec = epack[ee];
            col = rec.x;
            w   = __int_as_float(rec.y);
        }
        if (act) {
            const ushort4 v = *(const ushort4*)&xin[(size_t)col * N_CLASS + 4 * q];
            s.x += w * bf2f(v.x);
            s.y += w * bf2f(v.y);
            s.z += w * bf2f(v.z);
            s.w += w * bf2f(v.w);
        }
    }
    // reduce across the 4 slots
#pragma unroll
    for (int o = 16; o <= 32; o <<= 1) {
        s.x += __shfl_xor(s.x, o);
        s.y += __shfl_xor(s.y, o);
        s.z += __shfl_xor(s.z, o);
        s.w += __shfl_xor(s.w, o);
    }
    // attention score
    float tq = 0.f;
    if (act) {
        const float4 wa = *(const float4*)&Wa[4 * q];
        tq = s.x * wa.x + s.y * wa.y + s.z * wa.z + s.w * wa.w;
    }
#pragma unroll
    for (int o = 1; o < 16; o <<= 1) tq += __shfl_xor(tq, o);
    const float z  = tq + ba[0];
    const float sc = 1.f / (1.f + expf(-z));

    if (act && slot == 0) {
        ushort4 ov;
        ov.x = (unsigned short)f2bf(s.x);
        ov.y = (unsigned short)f2bf(s.y);
        ov.z = (unsigned short)f2bf(s.z);
        ov.w = (unsigned short)f2bf(s.w);
        *(ushort4*)&xout[(size_t)row * N_CLASS + 4 * q] = ov;
        float4* ap = (float4*)&acc[(size_t)row * N_CLASS + 4 * q];
        float4 a = *ap;
        a.x += sc * s.x; a.y += sc * s.y; a.z += sc * s.z; a.w += sc * s.w;
        *ap = a;
    }
}

// ---------------- log_softmax over 40 classes ----------------
__global__ __launch_bounds__(256) void logsoftmax_kernel(
    const float* __restrict__ acc, float* __restrict__ out)
{
    const int lane = threadIdx.x & 63;
    const int row  = blockIdx.x * 4 + (threadIdx.x >> 6);
    if (row >= N_NODES) return;
    const int  c   = lane;
    const bool act = c < N_CLASS;

    float v = act ? acc[(size_t)row * N_CLASS + c] : -INFINITY;
    float mx = v;
#pragma unroll
    for (int o = 32; o; o >>= 1) mx = fmaxf(mx, __shfl_xor(mx, o));
    const float e = act ? expf(v - mx) : 0.f;
    const float s = wave_sum(e);
    if (act) out[(size_t)row * N_CLASS + c] = v - mx - logf(s);
}

extern "C" void kernel_launch(void* const* d_in, const int* in_sizes, int n_in,
                              void* d_out, int out_size, void* d_ws, size_t ws_size,
                              hipStream_t stream)
{
    (void)in_sizes; (void)n_in; (void)out_size; (void)ws_size;
    const float* feat = (const float*)d_in[0];
    const int*   erow = (const int*)d_in[1];
    const int*   ecol = (const int*)d_in[2];
    const float* ew   = (const float*)d_in[3];
    const float* W1   = (const float*)d_in[4];
    const float* b1   = (const float*)d_in[5];
    const float* W2   = (const float*)d_in[6];
    const float* b2   = (const float*)d_in[7];
    const float* Wa   = (const float*)d_in[8];
    const float* ba   = (const float*)d_in[9];
    float* out = (float*)d_out;

    char* ws = (char*)d_ws;
    size_t off = 0;
    auto take = [&](size_t bytes) -> char* {
        char* p = ws + off;
        off += (bytes + 255) & ~(size_t)255;
        return p;
    };
    unsigned short* xb0 = (unsigned short*)take((size_t)N_NODES * N_CLASS * 2);
    unsigned short* xb1 = (unsigned short*)take((size_t)N_NODES * N_CLASS * 2);
    float* acc    = (float*)take((size_t)N_NODES * N_CLASS * 4);
    int*   deg    = (int*)take((size_t)N_NODES * 4);
    int*   rowptr = (int*)take((size_t)(N_NODES + 1) * 4);
    int*   cursor = (int*)take((size_t)N_NODES * 4);
    int*   parts  = (int*)take(4096);
    int*   spine  = (int*)take(4096);
    short* W1p    = (short*)take((size_t)N_FEAT * N_HID * 2);
    short* W2p    = (short*)take((size_t)N_HID * 48 * 2);
    int2*  epack  = (int2*)take((size_t)N_EDGES * 8);

    hipMemsetAsync(deg, 0, (size_t)N_NODES * 4, stream);

    pack_w1<<<16, 256, 0, stream>>>(W1, W1p);
    pack_w2<<<2, 256, 0, stream>>>(W2, W2p);
    mlp_mfma<<<(N_NODES + 63) / 64, 256, 0, stream>>>(feat, W1p, b1, W2p, b2, xb0);

    hist_kernel<<<N_EDGES / 256, 256, 0, stream>>>(erow, deg);
    scan_partial<<<NB_SCAN, 256, 0, stream>>>(deg, parts);
    scan_spine<<<1, 128, 0, stream>>>(parts, spine, rowptr);
    scan_final<<<NB_SCAN, 256, 0, stream>>>(deg, spine, rowptr, cursor);
    scatter_kernel<<<N_EDGES / 256, 256, 0, stream>>>(erow, ecol, ew, cursor, epack);

    attend0_kernel<<<N_NODES / 4, 256, 0, stream>>>(xb0, Wa, ba, acc);

    const unsigned short* xin = xb0;
    unsigned short* xout = xb1;
    for (int k = 0; k < K_HOPS; ++k) {
        hop_kernel<<<N_NODES / 4, 256, 0, stream>>>(rowptr, epack, xin, xout, acc, Wa, ba);
        unsigned short* tmp = (unsigned short*)xin;
        xin  = xout;
        xout = tmp;
    }

    logsoftmax_kernel<<<N_NODES / 4, 256, 0, stream>>>(acc, out);
}

// Round 4
// 1540.991 us; speedup vs baseline: 1.9294x; 1.2036x over previous
//
#include <hip/hip_runtime.h>
#include <math.h>

#define N_NODES 100000
#define N_EDGES 3200000
#define N_FEAT  512
#define N_HID   256
#define N_CLASS 40
#define K_HOPS  10

typedef __attribute__((ext_vector_type(8))) short short8;
typedef __attribute__((ext_vector_type(8))) unsigned short ushort8v;
typedef __attribute__((ext_vector_type(4))) float float4v;

__device__ inline short f2bf(float f)
{
    union { float f; unsigned u; } v; v.f = f;
    unsigned r = v.u + 0x7FFF + ((v.u >> 16) & 1);   // RNE
    return (short)(r >> 16);
}

__device__ inline float bf2f(unsigned short u)
{
    union { unsigned u; float f; } v; v.u = (unsigned)u << 16;
    return v.f;
}

// ---------------- weight packing (once per launch, trivial) ----------------
__global__ void pack_w1(const float* __restrict__ W1, short* __restrict__ W1p)
{
    const int id = blockIdx.x * 256 + threadIdx.x;   // 0..4095
    const int kb = id >> 8, n = id & 255;
    short tmp[32];
#pragma unroll
    for (int kl = 0; kl < 32; ++kl)
        tmp[kl] = f2bf(W1[(size_t)(kb * 32 + kl) * N_HID + n]);
    short8* dst = (short8*)&W1p[id * 32];
#pragma unroll
    for (int j = 0; j < 4; ++j) dst[j] = *(short8*)&tmp[j * 8];
}

__global__ void pack_w2(const float* __restrict__ W2, short* __restrict__ W2p)
{
    const int id = blockIdx.x * 256 + threadIdx.x;
    if (id >= 8 * 48) return;
    const int kb = id / 48, n = id % 48;
    short tmp[32];
#pragma unroll
    for (int kl = 0; kl < 32; ++kl)
        tmp[kl] = (n < N_CLASS) ? f2bf(W2[(size_t)(kb * 32 + kl) * N_CLASS + n]) : (short)0;
    short8* dst = (short8*)&W2p[id * 32];
#pragma unroll
    for (int j = 0; j < 4; ++j) dst[j] = *(short8*)&tmp[j * 8];
}

// ---------------- fused MFMA MLP: x0 = relu(feat@W1+b1)@W2 + b2 (bf16 out) ----
__global__ __launch_bounds__(256) void mlp_mfma(
    const float* __restrict__ feat, const short* __restrict__ W1p,
    const float* __restrict__ b1, const short* __restrict__ W2p,
    const float* __restrict__ b2, unsigned short* __restrict__ x0)
{
    __shared__ __align__(16) short smem[64 * 264];          // 33792 B
    short (*As)[40]  = (short(*)[40])smem;                  // aliased (phase 1)
    short (*Hs)[264] = (short(*)[264])smem;                 // aliased (phase 2)

    const int t    = threadIdx.x;
    const int wave = t >> 6;
    const int lane = t & 63;
    const int q    = lane >> 4;      // quad 0..3
    const int m    = lane & 15;
    const int n0   = blockIdx.x * 64;
    const int colbase = wave * 64;

    float4v acc[4][4];
#pragma unroll
    for (int i = 0; i < 4; ++i)
#pragma unroll
        for (int j = 0; j < 4; ++j) acc[i][j] = (float4v)0.f;

    for (int kb = 0; kb < 16; ++kb) {
        const int k0 = kb * 32;
        __syncthreads();
        {
            const int r  = t >> 2;
            const int kq = t & 3;
            const int n  = n0 + r;
            float f[8];
            if (n < N_NODES) {
                const float* p = &feat[(size_t)n * N_FEAT + k0 + 8 * kq];
                float4 v0 = *(const float4*)p;
                float4 v1 = *(const float4*)(p + 4);
                f[0]=v0.x; f[1]=v0.y; f[2]=v0.z; f[3]=v0.w;
                f[4]=v1.x; f[5]=v1.y; f[6]=v1.z; f[7]=v1.w;
            } else {
#pragma unroll
                for (int j = 0; j < 8; ++j) f[j] = 0.f;
            }
            short8 st;
#pragma unroll
            for (int j = 0; j < 8; ++j) st[j] = f2bf(f[j]);
            *(short8*)&As[r][8 * kq] = st;
        }
        __syncthreads();

        short8 af[4], bfr[4];
#pragma unroll
        for (int rt = 0; rt < 4; ++rt)
            af[rt] = *(const short8*)&As[rt * 16 + m][q * 8];
#pragma unroll
        for (int ct = 0; ct < 4; ++ct) {
            const int off = (kb * 256 + colbase + ct * 16 + m) * 32 + q * 8;
            bfr[ct] = *(const short8*)&W1p[off];
        }
#pragma unroll
        for (int rt = 0; rt < 4; ++rt)
#pragma unroll
            for (int ct = 0; ct < 4; ++ct)
                acc[rt][ct] = __builtin_amdgcn_mfma_f32_16x16x32_bf16(
                    af[rt], bfr[ct], acc[rt][ct], 0, 0, 0);
    }

    __syncthreads();
#pragma unroll
    for (int ct = 0; ct < 4; ++ct) {
        const int col = colbase + ct * 16 + m;
        const float bias = b1[col];
#pragma unroll
        for (int rt = 0; rt < 4; ++rt) {
            const float4v d = acc[rt][ct];
#pragma unroll
            for (int r = 0; r < 4; ++r) {
                const float hv = fmaxf(d[r] + bias, 0.f);
                Hs[rt * 16 + q * 4 + r][col] = f2bf(hv);
            }
        }
    }
    __syncthreads();

    float4v acc2[3];
#pragma unroll
    for (int ct = 0; ct < 3; ++ct) acc2[ct] = (float4v)0.f;
#pragma unroll
    for (int kb = 0; kb < 8; ++kb) {
        const short8 a2 = *(const short8*)&Hs[wave * 16 + m][kb * 32 + q * 8];
#pragma unroll
        for (int ct = 0; ct < 3; ++ct) {
            const int off = (kb * 48 + ct * 16 + m) * 32 + q * 8;
            const short8 b2f = *(const short8*)&W2p[off];
            acc2[ct] = __builtin_amdgcn_mfma_f32_16x16x32_bf16(a2, b2f, acc2[ct], 0, 0, 0);
        }
    }
#pragma unroll
    for (int ct = 0; ct < 3; ++ct) {
        const int col = ct * 16 + m;
        if (col < N_CLASS) {
            const float bias = b2[col];
#pragma unroll
            for (int r = 0; r < 4; ++r) {
                const int row = n0 + wave * 16 + q * 4 + r;
                if (row < N_NODES)
                    x0[(size_t)row * N_CLASS + col] = (unsigned short)f2bf(acc2[ct][r] + bias);
            }
        }
    }
}

// ---------------- CSR build ----------------
// 8 edges/thread, vectorized loads, fire-and-forget atomics
__global__ __launch_bounds__(256) void hist_kernel(const int* __restrict__ erow,
                                                   int* __restrict__ deg)
{
    const int t = blockIdx.x * 256 + threadIdx.x;
    const int base = t * 8;
    if (base >= N_EDGES) return;
    const int4 r0 = *(const int4*)&erow[base];
    const int4 r1 = *(const int4*)&erow[base + 4];
    atomicAdd(&deg[r0.x], 1); atomicAdd(&deg[r0.y], 1);
    atomicAdd(&deg[r0.z], 1); atomicAdd(&deg[r0.w], 1);
    atomicAdd(&deg[r1.x], 1); atomicAdd(&deg[r1.y], 1);
    atomicAdd(&deg[r1.z], 1); atomicAdd(&deg[r1.w], 1);
}

__global__ void scan_partial(const int* __restrict__ deg, int* __restrict__ parts)
{
    __shared__ int sm[256];
    const int b = blockIdx.x, t = threadIdx.x;
    const int base = b * 1024 + t * 4;
    int s = 0;
#pragma unroll
    for (int u = 0; u < 4; ++u) {
        const int i = base + u;
        if (i < N_NODES) s += deg[i];
    }
    sm[t] = s;
    __syncthreads();
    for (int off = 128; off; off >>= 1) {
        if (t < off) sm[t] += sm[t + off];
        __syncthreads();
    }
    if (t == 0) parts[b] = sm[0];
}

#define NB_SCAN 98   // ceil(100000/1024)

__global__ void scan_spine(const int* __restrict__ parts, int* __restrict__ spine,
                           int* __restrict__ rowptr)
{
    __shared__ int sm[128];
    const int t = threadIdx.x;
    const int v = (t < NB_SCAN) ? parts[t] : 0;
    sm[t] = v;
    __syncthreads();
    for (int off = 1; off < 128; off <<= 1) {
        const int u = (t >= off) ? sm[t - off] : 0;
        __syncthreads();
        sm[t] += u;
        __syncthreads();
    }
    if (t < NB_SCAN) spine[t] = sm[t] - v;          // exclusive
    if (t == NB_SCAN - 1) rowptr[N_NODES] = sm[t];  // total = N_EDGES
}

__global__ void scan_final(const int* __restrict__ deg, const int* __restrict__ spine,
                           int* __restrict__ rowptr, int* __restrict__ cursor)
{
    __shared__ int sm[256];
    const int b = blockIdx.x, t = threadIdx.x;
    const int base = b * 1024 + t * 4;
    int d[4];
    int s = 0;
#pragma unroll
    for (int u = 0; u < 4; ++u) {
        const int i = base + u;
        d[u] = (i < N_NODES) ? deg[i] : 0;
        s += d[u];
    }
    sm[t] = s;
    __syncthreads();
    for (int off = 1; off < 256; off <<= 1) {
        const int u = (t >= off) ? sm[t - off] : 0;
        __syncthreads();
        sm[t] += u;
        __syncthreads();
    }
    int ex = sm[t] - s + spine[b];
#pragma unroll
    for (int u = 0; u < 4; ++u) {
        const int i = base + u;
        if (i < N_NODES) {
            rowptr[i] = ex;
            cursor[i] = ex;
            ex += d[u];
        }
    }
}

// 8 edges/thread: 8 independent atomics in flight, then 8 stores (MLP on the
// atomic->store latency chain)
__global__ __launch_bounds__(256) void scatter_kernel(
    const int* __restrict__ erow, const int* __restrict__ ecol,
    const float* __restrict__ ew, int* __restrict__ cursor,
    int2* __restrict__ epack)
{
    const int t = blockIdx.x * 256 + threadIdx.x;
    const int base = t * 8;
    if (base >= N_EDGES) return;
    const int4   r0 = *(const int4*)&erow[base];
    const int4   r1 = *(const int4*)&erow[base + 4];
    const int4   c0 = *(const int4*)&ecol[base];
    const int4   c1 = *(const int4*)&ecol[base + 4];
    const float4 w0 = *(const float4*)&ew[base];
    const float4 w1 = *(const float4*)&ew[base + 4];
    const int   rr[8] = {r0.x, r0.y, r0.z, r0.w, r1.x, r1.y, r1.z, r1.w};
    const int   cc[8] = {c0.x, c0.y, c0.z, c0.w, c1.x, c1.y, c1.z, c1.w};
    const float ww[8] = {w0.x, w0.y, w0.z, w0.w, w1.x, w1.y, w1.z, w1.w};
    int pp[8];
#pragma unroll
    for (int j = 0; j < 8; ++j) pp[j] = atomicAdd(&cursor[rr[j]], 1);
#pragma unroll
    for (int j = 0; j < 8; ++j) {
        int2 rec;
        rec.x = cc[j];
        rec.y = __float_as_int(ww[j]);
        epack[pp[j]] = rec;
    }
}

// ---------------- attention init (hop 0) ----------------
__device__ inline float wave_sum(float v)
{
#pragma unroll
    for (int o = 32; o; o >>= 1) v += __shfl_xor(v, o);
    return v;
}

__global__ __launch_bounds__(256) void attend0_kernel(
    const unsigned short* __restrict__ x, const float* __restrict__ Wa,
    const float* __restrict__ ba, float* __restrict__ acc)
{
    const int lane = threadIdx.x & 63;
    const int row  = blockIdx.x * 4 + (threadIdx.x >> 6);
    if (row >= N_NODES) return;
    const int  c   = lane;
    const bool act = c < N_CLASS;
    const float v  = act ? bf2f(x[(size_t)row * N_CLASS + c]) : 0.f;
    const float tt = act ? v * Wa[c] : 0.f;
    const float z  = wave_sum(tt) + ba[0];
    const float sc = 1.f / (1.f + expf(-z));
    if (act) acc[(size_t)row * N_CLASS + c] = sc * v;
}

// ------- one hop: s = segsum(w * xin[col]) fp32 from bf16 gathers;
//         xout = bf16(s); acc += sigmoid(s.Wa+ba) * s
// wave per row; slot = lane>>3 (8 edges in flight), l = lane&7 (5 active,
// each loads 16 B = 8 bf16 classes).
__global__ __launch_bounds__(256) void hop_kernel(
    const int* __restrict__ rowptr, const int2* __restrict__ epack,
    const unsigned short* __restrict__ xin,
    unsigned short* __restrict__ xout, float* __restrict__ acc,
    const float* __restrict__ Wa, const float* __restrict__ ba)
{
    const int lane = threadIdx.x & 63;
    const int row  = blockIdx.x * 4 + (threadIdx.x >> 6);
    if (row >= N_NODES) return;
    const int  slot = lane >> 3;     // 0..7
    const int  l    = lane & 7;      // 0..7; classes [8l, 8l+8) if l<5
    const bool act  = l < 5;

    const int e0 = rowptr[row];
    const int e1 = rowptr[row + 1];

    float s[8];
#pragma unroll
    for (int j = 0; j < 8; ++j) s[j] = 0.f;

    for (int e = e0; e < e1; e += 8) {
        const int ee = e + slot;
        int   col = 0;
        float w   = 0.f;
        if (ee < e1) {
            const int2 rec = epack[ee];   // same addr across the slot's 8 lanes
            col = rec.x;
            w   = __int_as_float(rec.y);
        }
        if (act) {
            const ushort8v v = *(const ushort8v*)&xin[(size_t)col * N_CLASS + l * 8];
#pragma unroll
            for (int j = 0; j < 8; ++j) s[j] += w * bf2f(v[j]);
        }
    }
    // reduce across the 8 slots (xor bits 3,4,5)
#pragma unroll
    for (int o = 8; o <= 32; o <<= 1)
#pragma unroll
        for (int j = 0; j < 8; ++j) s[j] += __shfl_xor(s[j], o);

    // attention score: per-lane partial over its 8 classes, reduce over l
    float tq = 0.f;
    if (act) {
#pragma unroll
        for (int j = 0; j < 8; ++j) tq += s[j] * Wa[l * 8 + j];
    }
#pragma unroll
    for (int o = 1; o <= 4; o <<= 1) tq += __shfl_xor(tq, o);
    const float z  = tq + ba[0];
    const float sc = 1.f / (1.f + expf(-z));

    if (act && slot == 0) {
        ushort8v ov;
#pragma unroll
        for (int j = 0; j < 8; ++j) ov[j] = (unsigned short)f2bf(s[j]);
        *(ushort8v*)&xout[(size_t)row * N_CLASS + l * 8] = ov;

        float4* ap0 = (float4*)&acc[(size_t)row * N_CLASS + l * 8];
        float4 a0 = ap0[0];
        float4 a1 = ap0[1];
        a0.x += sc * s[0]; a0.y += sc * s[1]; a0.z += sc * s[2]; a0.w += sc * s[3];
        a1.x += sc * s[4]; a1.y += sc * s[5]; a1.z += sc * s[6]; a1.w += sc * s[7];
        ap0[0] = a0;
        ap0[1] = a1;
    }
}

// ---------------- log_softmax over 40 classes ----------------
__global__ __launch_bounds__(256) void logsoftmax_kernel(
    const float* __restrict__ acc, float* __restrict__ out)
{
    const int lane = threadIdx.x & 63;
    const int row  = blockIdx.x * 4 + (threadIdx.x >> 6);
    if (row >= N_NODES) return;
    const int  c   = lane;
    const bool act = c < N_CLASS;

    float v = act ? acc[(size_t)row * N_CLASS + c] : -INFINITY;
    float mx = v;
#pragma unroll
    for (int o = 32; o; o >>= 1) mx = fmaxf(mx, __shfl_xor(mx, o));
    const float e = act ? expf(v - mx) : 0.f;
    const float s = wave_sum(e);
    if (act) out[(size_t)row * N_CLASS + c] = v - mx - logf(s);
}

extern "C" void kernel_launch(void* const* d_in, const int* in_sizes, int n_in,
                              void* d_out, int out_size, void* d_ws, size_t ws_size,
                              hipStream_t stream)
{
    (void)in_sizes; (void)n_in; (void)out_size; (void)ws_size;
    const float* feat = (const float*)d_in[0];
    const int*   erow = (const int*)d_in[1];
    const int*   ecol = (const int*)d_in[2];
    const float* ew   = (const float*)d_in[3];
    const float* W1   = (const float*)d_in[4];
    const float* b1   = (const float*)d_in[5];
    const float* W2   = (const float*)d_in[6];
    const float* b2   = (const float*)d_in[7];
    const float* Wa   = (const float*)d_in[8];
    const float* ba   = (const float*)d_in[9];
    float* out = (float*)d_out;

    char* ws = (char*)d_ws;
    size_t off = 0;
    auto take = [&](size_t bytes) -> char* {
        char* p = ws + off;
        off += (bytes + 255) & ~(size_t)255;
        return p;
    };
    unsigned short* xb0 = (unsigned short*)take((size_t)N_NODES * N_CLASS * 2 + 64);
    unsigned short* xb1 = (unsigned short*)take((size_t)N_NODES * N_CLASS * 2 + 64);
    float* acc    = (float*)take((size_t)N_NODES * N_CLASS * 4);
    int*   deg    = (int*)take((size_t)N_NODES * 4);
    int*   rowptr = (int*)take((size_t)(N_NODES + 1) * 4);
    int*   cursor = (int*)take((size_t)N_NODES * 4);
    int*   parts  = (int*)take(4096);
    int*   spine  = (int*)take(4096);
    short* W1p    = (short*)take((size_t)N_FEAT * N_HID * 2);
    short* W2p    = (short*)take((size_t)N_HID * 48 * 2);
    int2*  epack  = (int2*)take((size_t)N_EDGES * 8);

    hipMemsetAsync(deg, 0, (size_t)N_NODES * 4, stream);

    pack_w1<<<16, 256, 0, stream>>>(W1, W1p);
    pack_w2<<<2, 256, 0, stream>>>(W2, W2p);
    mlp_mfma<<<(N_NODES + 63) / 64, 256, 0, stream>>>(feat, W1p, b1, W2p, b2, xb0);

    const int ethreads = N_EDGES / 8;                       // 400000
    hist_kernel<<<(ethreads + 255) / 256, 256, 0, stream>>>(erow, deg);
    scan_partial<<<NB_SCAN, 256, 0, stream>>>(deg, parts);
    scan_spine<<<1, 128, 0, stream>>>(parts, spine, rowptr);
    scan_final<<<NB_SCAN, 256, 0, stream>>>(deg, spine, rowptr, cursor);
    scatter_kernel<<<(ethreads + 255) / 256, 256, 0, stream>>>(erow, ecol, ew, cursor, epack);

    attend0_kernel<<<N_NODES / 4, 256, 0, stream>>>(xb0, Wa, ba, acc);

    const unsigned short* xin = xb0;
    unsigned short* xout = xb1;
    for (int k = 0; k < K_HOPS; ++k) {
        hop_kernel<<<N_NODES / 4, 256, 0, stream>>>(rowptr, epack, xin, xout, acc, Wa, ba);
        unsigned short* tmp = (unsigned short*)xin;
        xin  = xout;
        xout = tmp;
    }

    logsoftmax_kernel<<<N_NODES / 4, 256, 0, stream>>>(acc, out);
}